// Round 6
// baseline (411.299 us; speedup 1.0000x reference)
//
#include <hip/hip_runtime.h>
#include <hip/hip_bf16.h>
#include <cstdint>

// Problem constants (from reference)
#define N_ENT  50000
#define N_EDGE 500000
#define D_IN   256
constexpr int ETOT = N_EDGE + N_ENT;

typedef __attribute__((ext_vector_type(8))) short bfrag;   // 8 bf16 (4 VGPRs)
typedef __attribute__((ext_vector_type(4))) float f4acc;   // 4 fp32 acc
typedef __attribute__((ext_vector_type(4))) float f32x4;   // NT-capable float4
typedef __attribute__((ext_vector_type(8))) short s16x8;   // NT-capable 8xbf16

__device__ __forceinline__ float lrelu(float x) { return x > 0.f ? x : 0.2f * x; }
__device__ __forceinline__ float eluf(float x)  { return x > 0.f ? x : (expf(x) - 1.f); }
__device__ __forceinline__ short to_bf16(float f) {
    __hip_bfloat16 b = __float2bfloat16(f);
    return *(short*)&b;
}
// two packed bf16 -> two floats (lo = bits[15:0], hi = bits[31:16])
__device__ __forceinline__ float2 bf2_to_f32(unsigned int u) {
    float2 r;
    r.x = __uint_as_float(u << 16);
    r.y = __uint_as_float(u & 0xffff0000u);
    return r;
}

// ---------------- LayerNorm: wave per row, bf16 output ----------------
// x is read exactly once -> non-temporal loads (keep cache for gather tables).
__global__ __launch_bounds__(256) void ln_kernel(const float* __restrict__ x,
        const float* __restrict__ w, const float* __restrict__ b,
        short* __restrict__ y)
{
    int n = blockIdx.x * 4 + (threadIdx.x >> 6);
    int lane = threadIdx.x & 63;
    const f32x4 v = __builtin_nontemporal_load((const f32x4*)(x + (size_t)n * D_IN + lane * 4));
    float s  = v.x + v.y + v.z + v.w;
    float sq = v.x*v.x + v.y*v.y + v.z*v.z + v.w*v.w;
    #pragma unroll
    for (int off = 1; off < 64; off <<= 1) {
        s  += __shfl_xor(s, off);
        sq += __shfl_xor(sq, off);
    }
    float mean = s * (1.f / 256.f);
    float var  = sq * (1.f / 256.f) - mean * mean;
    float rstd = rsqrtf(var + 1e-5f);
    float4 wv = *(const float4*)(w + lane * 4);
    float4 bv = *(const float4*)(b + lane * 4);
    short4 o;
    o.x = to_bf16((v.x - mean) * rstd * wv.x + bv.x);
    o.y = to_bf16((v.y - mean) * rstd * wv.y + bv.y);
    o.z = to_bf16((v.z - mean) * rstd * wv.z + bv.z);
    o.w = to_bf16((v.w - mean) * rstd * wv.w + bv.w);
    *(short4*)(y + (size_t)n * D_IN + lane * 4) = o;
}

// ---------------- transpose + cast: W[R,C] f32 -> WT[C,R] bf16 ----------------
__global__ __launch_bounds__(256) void transpose_bf16_kernel(const float* __restrict__ W,
        short* __restrict__ WT, int R, int C)
{
    int i = blockIdx.x * 256 + threadIdx.x;
    if (i >= R * C) return;
    int r = i / C, c = i - r * C;
    WT[c * R + r] = to_bf16(W[i]);
}

// ---------------- bf16 MFMA GEMM + fused attention dots ----------------
// C[M,NN] = A[M,KK] @ BT[NN,KK]^T, bf16 out.
// CH = head width in columns (64 for conv1, 256 for conv2).
// Epilogue also computes a_s[row,head] = sum_c C[row,c]*att_s[c] (per head)
// from the fp32 accumulators: per-lane partial over its 4 j-columns, then
// shfl reduction over the 16-lane ln16 group. For CH<=64 each (row,head)
// has exactly one writer wave -> plain store; else atomicAdd (zero-init'd).
template<int NN, int KK, int CH>
__global__ __launch_bounds__(256) void gemm_mfma(const short* __restrict__ A,
        const short* __restrict__ BT, short* __restrict__ C,
        const float* __restrict__ att_s, const float* __restrict__ att_d,
        float* __restrict__ a_s, float* __restrict__ a_d, int M)
{
    __shared__ short As[128 * 32];
    __shared__ short Bs[128 * 32];
    const int tid  = threadIdx.x;
    const int w    = tid >> 6;
    const int l    = tid & 63;
    const int wm   = w >> 1, wn = w & 1;
    const int m0   = blockIdx.y * 128;
    const int n0   = blockIdx.x * 128;
    const int quad = l >> 4;
    const int ln16 = l & 15;
    const int rl   = l >> 2;   // staging: row within 16-row issue group
    const int cs   = l & 3;    // staging: chunk slot

    f4acc acc[4][4];
    #pragma unroll
    for (int i = 0; i < 4; ++i)
        #pragma unroll
        for (int j = 0; j < 4; ++j)
            acc[i][j] = (f4acc){0.f, 0.f, 0.f, 0.f};

    for (int k0 = 0; k0 < KK; k0 += 32) {
        __syncthreads();
        #pragma unroll
        for (int tt = 0; tt < 2; ++tt) {
            int t   = w * 2 + tt;          // issue id 0..7 (16 rows each)
            int row = t * 16 + rl;         // local row 0..127
            int ca  = cs ^ ((row >> 1) & 3);
            const short* ga = A + (size_t)(m0 + row) * KK + k0 + ca * 8;
            __builtin_amdgcn_global_load_lds(
                (const __attribute__((address_space(1))) unsigned int*)ga,
                (__attribute__((address_space(3))) unsigned int*)&As[t * 512], 16, 0, 0);
            const short* gb = BT + (size_t)(n0 + row) * KK + k0 + ca * 8;
            __builtin_amdgcn_global_load_lds(
                (const __attribute__((address_space(1))) unsigned int*)gb,
                (__attribute__((address_space(3))) unsigned int*)&Bs[t * 512], 16, 0, 0);
        }
        __syncthreads();
        bfrag af[4], bf[4];
        #pragma unroll
        for (int i = 0; i < 4; ++i) {
            int r = wm * 64 + i * 16 + ln16;           // A row (m)
            af[i] = *(const bfrag*)&As[r * 32 + (quad ^ ((r >> 1) & 3)) * 8];
            int rn = wn * 64 + i * 16 + ln16;          // B col (n)
            bf[i] = *(const bfrag*)&Bs[rn * 32 + (quad ^ ((rn >> 1) & 3)) * 8];
        }
        #pragma unroll
        for (int i = 0; i < 4; ++i)
            #pragma unroll
            for (int j = 0; j < 4; ++j)
                acc[i][j] = __builtin_amdgcn_mfma_f32_16x16x32_bf16(af[i], bf[j], acc[i][j], 0, 0, 0);
    }

    // att coefficients for this lane's 4 owned columns (all in one head:
    // cols n0+wn*64 .. +63 span exactly one head for CH>=64)
    const int hh = (n0 + wn * 64) / CH;
    float as_c[4], ad_c[4];
    #pragma unroll
    for (int j = 0; j < 4; ++j) {
        int gc = n0 + wn * 64 + j * 16 + ln16;
        as_c[j] = att_s[gc];
        ad_c[j] = att_d[gc];
    }

    // epilogue: C/D layout col=lane&15, row=quad*4+reg; bf16 store + dots
    #pragma unroll
    for (int i = 0; i < 4; ++i) {
        #pragma unroll
        for (int p = 0; p < 4; ++p) {
            int gr = m0 + wm * 64 + i * 16 + quad * 4 + p;
            float ps = 0.f, pd = 0.f;
            #pragma unroll
            for (int j = 0; j < 4; ++j) {
                float c = acc[i][j][p];
                ps = fmaf(c, as_c[j], ps);
                pd = fmaf(c, ad_c[j], pd);
            }
            // reduce over the 16 lanes sharing (quad); xor offsets stay in-group
            #pragma unroll
            for (int off = 1; off < 16; off <<= 1) {
                ps += __shfl_xor(ps, off);
                pd += __shfl_xor(pd, off);
            }
            if (gr < M) {
                #pragma unroll
                for (int j = 0; j < 4; ++j) {
                    int gc = n0 + wn * 64 + j * 16 + ln16;
                    C[(size_t)gr * NN + gc] = to_bf16(acc[i][j][p]);
                }
                if (ln16 == 0) {
                    if constexpr (CH <= 64) {
                        a_s[(size_t)gr * (NN / CH) + hh] = ps;
                        a_d[(size_t)gr * (NN / CH) + hh] = pd;
                    } else {
                        unsafeAtomicAdd(&a_s[gr], ps);
                        unsafeAtomicAdd(&a_d[gr], pd);
                    }
                }
            }
        }
    }
}

// ---------------- CSR build ----------------
__global__ __launch_bounds__(256) void count_kernel(const int* __restrict__ ei,
        int* __restrict__ cnt)
{
    int e = blockIdx.x * 256 + threadIdx.x;
    if (e < N_EDGE) atomicAdd(&cnt[ei[N_EDGE + e]], 1);
}

__global__ __launch_bounds__(256) void alloc_kernel(const int* __restrict__ cnt,
        int* __restrict__ row_start, int* __restrict__ cursor)
{
    int d = blockIdx.x * 256 + threadIdx.x;
    int lane = threadIdx.x & 63;
    int c = (d < N_ENT) ? cnt[d] : 0;
    int inc = c;
    #pragma unroll
    for (int off = 1; off < 64; off <<= 1) {
        int nb = __shfl_up(inc, off);
        if (lane >= off) inc += nb;
    }
    int waveTotal = __shfl(inc, 63);
    int base = 0;
    if (lane == 63) base = atomicAdd(cursor, waveTotal);
    base = __shfl(base, 63);
    if (d < N_ENT) row_start[d] = base + inc - c;
}

__global__ __launch_bounds__(256) void fill_csr_kernel(const int* __restrict__ ei,
        const int* __restrict__ row_start, int* __restrict__ cursor2,
        int* __restrict__ csr_src)
{
    int e = blockIdx.x * 256 + threadIdx.x;
    if (e >= N_EDGE) return;
    int d = ei[N_EDGE + e];
    int pos = atomicAdd(&cursor2[d], 1);
    csr_src[row_start[d] + pos] = ei[e];
}

// ---------------- conv1 aggregation: wave per dst, one-pass softmax ----------------
// H=8, C=64, F=512. lane owns 8 contiguous bf16 (16 B); head h = lane>>3.
// No segment-max (shift-invariant, |e|<=~3 so exp can't overflow).
// Output h2b is a pure stream for gemm2 -> non-temporal 16B store.
__global__ __launch_bounds__(256) void aggr1_kernel(const int* __restrict__ csr_src,
        const int* __restrict__ row_start, const int* __restrict__ cnt,
        const short* __restrict__ feat, const float* __restrict__ a_s,
        const float* __restrict__ a_d, const float* __restrict__ bias,
        short* __restrict__ out)
{
    int d = blockIdx.x * 4 + (threadIdx.x >> 6);
    if (d >= N_ENT) return;
    int lane = threadIdx.x & 63;
    int f0 = lane * 8;
    int h = lane >> 3;
    int rs = row_start[d];
    int n = cnt[d];
    float adh = a_d[d * 8 + h];

    float den = 0.f;
    float acc[8] = {0.f, 0.f, 0.f, 0.f, 0.f, 0.f, 0.f, 0.f};
    // self loop
    {
        float p = expf(lrelu(a_s[d * 8 + h] + adh));
        den += p;
        uint4 rv = *(const uint4*)(feat + (size_t)d * 512 + f0);
        float2 t0 = bf2_to_f32(rv.x), t1 = bf2_to_f32(rv.y);
        float2 t2 = bf2_to_f32(rv.z), t3 = bf2_to_f32(rv.w);
        acc[0] += p * t0.x; acc[1] += p * t0.y; acc[2] += p * t1.x; acc[3] += p * t1.y;
        acc[4] += p * t2.x; acc[5] += p * t2.y; acc[6] += p * t3.x; acc[7] += p * t3.y;
    }
    int i = 0;
    for (; i + 4 <= n; i += 4) {
        int s0 = csr_src[rs + i + 0];
        int s1 = csr_src[rs + i + 1];
        int s2 = csr_src[rs + i + 2];
        int s3 = csr_src[rs + i + 3];
        float e0 = a_s[s0 * 8 + h], e1 = a_s[s1 * 8 + h];
        float e2 = a_s[s2 * 8 + h], e3 = a_s[s3 * 8 + h];
        uint4 rv0 = *(const uint4*)(feat + (size_t)s0 * 512 + f0);
        uint4 rv1 = *(const uint4*)(feat + (size_t)s1 * 512 + f0);
        uint4 rv2 = *(const uint4*)(feat + (size_t)s2 * 512 + f0);
        uint4 rv3 = *(const uint4*)(feat + (size_t)s3 * 512 + f0);
        float p0 = expf(lrelu(e0 + adh));
        float p1 = expf(lrelu(e1 + adh));
        float p2 = expf(lrelu(e2 + adh));
        float p3 = expf(lrelu(e3 + adh));
        den += (p0 + p1) + (p2 + p3);
        float2 t0, t1, t2, t3;
        t0 = bf2_to_f32(rv0.x); t1 = bf2_to_f32(rv0.y); t2 = bf2_to_f32(rv0.z); t3 = bf2_to_f32(rv0.w);
        acc[0] += p0 * t0.x; acc[1] += p0 * t0.y; acc[2] += p0 * t1.x; acc[3] += p0 * t1.y;
        acc[4] += p0 * t2.x; acc[5] += p0 * t2.y; acc[6] += p0 * t3.x; acc[7] += p0 * t3.y;
        t0 = bf2_to_f32(rv1.x); t1 = bf2_to_f32(rv1.y); t2 = bf2_to_f32(rv1.z); t3 = bf2_to_f32(rv1.w);
        acc[0] += p1 * t0.x; acc[1] += p1 * t0.y; acc[2] += p1 * t1.x; acc[3] += p1 * t1.y;
        acc[4] += p1 * t2.x; acc[5] += p1 * t2.y; acc[6] += p1 * t3.x; acc[7] += p1 * t3.y;
        t0 = bf2_to_f32(rv2.x); t1 = bf2_to_f32(rv2.y); t2 = bf2_to_f32(rv2.z); t3 = bf2_to_f32(rv2.w);
        acc[0] += p2 * t0.x; acc[1] += p2 * t0.y; acc[2] += p2 * t1.x; acc[3] += p2 * t1.y;
        acc[4] += p2 * t2.x; acc[5] += p2 * t2.y; acc[6] += p2 * t3.x; acc[7] += p2 * t3.y;
        t0 = bf2_to_f32(rv3.x); t1 = bf2_to_f32(rv3.y); t2 = bf2_to_f32(rv3.z); t3 = bf2_to_f32(rv3.w);
        acc[0] += p3 * t0.x; acc[1] += p3 * t0.y; acc[2] += p3 * t1.x; acc[3] += p3 * t1.y;
        acc[4] += p3 * t2.x; acc[5] += p3 * t2.y; acc[6] += p3 * t3.x; acc[7] += p3 * t3.y;
    }
    for (; i < n; ++i) {
        int s = csr_src[rs + i];
        float p = expf(lrelu(a_s[s * 8 + h] + adh));
        den += p;
        uint4 rv = *(const uint4*)(feat + (size_t)s * 512 + f0);
        float2 t0 = bf2_to_f32(rv.x), t1 = bf2_to_f32(rv.y);
        float2 t2 = bf2_to_f32(rv.z), t3 = bf2_to_f32(rv.w);
        acc[0] += p * t0.x; acc[1] += p * t0.y; acc[2] += p * t1.x; acc[3] += p * t1.y;
        acc[4] += p * t2.x; acc[5] += p * t2.y; acc[6] += p * t3.x; acc[7] += p * t3.y;
    }
    float inv = 1.f / den;
    float4 b0 = *(const float4*)(bias + f0);
    float4 b1 = *(const float4*)(bias + f0 + 4);
    s16x8 o;
    o[0] = to_bf16(eluf(acc[0] * inv + b0.x)); o[1] = to_bf16(eluf(acc[1] * inv + b0.y));
    o[2] = to_bf16(eluf(acc[2] * inv + b0.z)); o[3] = to_bf16(eluf(acc[3] * inv + b0.w));
    o[4] = to_bf16(eluf(acc[4] * inv + b1.x)); o[5] = to_bf16(eluf(acc[5] * inv + b1.y));
    o[6] = to_bf16(eluf(acc[6] * inv + b1.z)); o[7] = to_bf16(eluf(acc[7] * inv + b1.w));
    __builtin_nontemporal_store(o, (s16x8*)(out + (size_t)d * 512 + f0));
}

// ---------------- conv2 aggregation: wave per dst, one-pass softmax ----------------
// H=1, C=256, F=256. lane owns 4 bf16 (8 B). Final output -> NT store.
__global__ __launch_bounds__(256) void aggr2_kernel(const int* __restrict__ csr_src,
        const int* __restrict__ row_start, const int* __restrict__ cnt,
        const short* __restrict__ feat, const float* __restrict__ a_s,
        const float* __restrict__ a_d, const float* __restrict__ bias,
        float* __restrict__ out)
{
    int d = blockIdx.x * 4 + (threadIdx.x >> 6);
    if (d >= N_ENT) return;
    int lane = threadIdx.x & 63;
    int f0 = lane * 4;
    int rs = row_start[d];
    int n = cnt[d];
    float adh = a_d[d];

    float den = 0.f;
    float4 acc = make_float4(0.f, 0.f, 0.f, 0.f);
    {
        float p = expf(lrelu(a_s[d] + adh));
        den += p;
        uint2 rv = *(const uint2*)(feat + (size_t)d * 256 + f0);
        float2 t0 = bf2_to_f32(rv.x), t1 = bf2_to_f32(rv.y);
        acc.x += p * t0.x; acc.y += p * t0.y; acc.z += p * t1.x; acc.w += p * t1.y;
    }
    int i = 0;
    for (; i + 4 <= n; i += 4) {
        int s0 = csr_src[rs + i + 0];
        int s1 = csr_src[rs + i + 1];
        int s2 = csr_src[rs + i + 2];
        int s3 = csr_src[rs + i + 3];
        float e0 = a_s[s0], e1 = a_s[s1], e2 = a_s[s2], e3 = a_s[s3];
        uint2 rv0 = *(const uint2*)(feat + (size_t)s0 * 256 + f0);
        uint2 rv1 = *(const uint2*)(feat + (size_t)s1 * 256 + f0);
        uint2 rv2 = *(const uint2*)(feat + (size_t)s2 * 256 + f0);
        uint2 rv3 = *(const uint2*)(feat + (size_t)s3 * 256 + f0);
        float p0 = expf(lrelu(e0 + adh));
        float p1 = expf(lrelu(e1 + adh));
        float p2 = expf(lrelu(e2 + adh));
        float p3 = expf(lrelu(e3 + adh));
        den += (p0 + p1) + (p2 + p3);
        float2 t0, t1;
        t0 = bf2_to_f32(rv0.x); t1 = bf2_to_f32(rv0.y);
        acc.x += p0 * t0.x; acc.y += p0 * t0.y; acc.z += p0 * t1.x; acc.w += p0 * t1.y;
        t0 = bf2_to_f32(rv1.x); t1 = bf2_to_f32(rv1.y);
        acc.x += p1 * t0.x; acc.y += p1 * t0.y; acc.z += p1 * t1.x; acc.w += p1 * t1.y;
        t0 = bf2_to_f32(rv2.x); t1 = bf2_to_f32(rv2.y);
        acc.x += p2 * t0.x; acc.y += p2 * t0.y; acc.z += p2 * t1.x; acc.w += p2 * t1.y;
        t0 = bf2_to_f32(rv3.x); t1 = bf2_to_f32(rv3.y);
        acc.x += p3 * t0.x; acc.y += p3 * t0.y; acc.z += p3 * t1.x; acc.w += p3 * t1.y;
    }
    for (; i < n; ++i) {
        int s = csr_src[rs + i];
        float p = expf(lrelu(a_s[s] + adh));
        den += p;
        uint2 rv = *(const uint2*)(feat + (size_t)s * 256 + f0);
        float2 t0 = bf2_to_f32(rv.x), t1 = bf2_to_f32(rv.y);
        acc.x += p * t0.x; acc.y += p * t0.y; acc.z += p * t1.x; acc.w += p * t1.y;
    }
    float inv = 1.f / den;
    float4 bv = *(const float4*)(bias + f0);
    f32x4 o;
    o.x = acc.x * inv + bv.x; o.y = acc.y * inv + bv.y;
    o.z = acc.z * inv + bv.z; o.w = acc.w * inv + bv.w;
    __builtin_nontemporal_store(o, (f32x4*)(out + (size_t)d * 256 + f0));
}

extern "C" void kernel_launch(void* const* d_in, const int* in_sizes, int n_in,
                              void* d_out, int out_size, void* d_ws, size_t ws_size,
                              hipStream_t stream)
{
    const int*   ei     = (const int*)  d_in[0];
    const float* x      = (const float*)d_in[1];
    const float* ln_w   = (const float*)d_in[2];
    const float* ln_b   = (const float*)d_in[3];
    const float* W1     = (const float*)d_in[4];
    const float* att_s1 = (const float*)d_in[5];
    const float* att_d1 = (const float*)d_in[6];
    const float* b1     = (const float*)d_in[7];
    const float* W2     = (const float*)d_in[8];
    const float* att_s2 = (const float*)d_in[9];
    const float* att_d2 = (const float*)d_in[10];
    const float* b2     = (const float*)d_in[11];
    float* out = (float*)d_out;

    short* h0b = (short*)d_ws;                // [50000,256] bf16 LN out
    short* h1b = h0b + 12800000;              // [50000,512] bf16 gemm1 out
    short* h2b = h1b + 25600000;              // [50000,512] bf16 conv1 out
    short* h3b = h2b + 25600000;              // [50000,256] bf16 gemm2 out
    short* W1T = h3b + 12800000;              // [512,256] bf16
    short* W2T = W1T + 131072;                // [256,512] bf16
    float* a_s1 = (float*)(W2T + 131072);     // [50000,8]
    float* a_d1 = a_s1 + 400000;
    float* a_s2 = a_d1 + 400000;              // [50000]
    float* a_d2 = a_s2 + 50000;
    int* cnt       = (int*)(a_d2 + 50000);    // 50000
    int* row_start = cnt + 50000;
    int* cursor2   = row_start + 50000;
    int* csr_src   = cursor2 + 50000;         // 500000
    int* cursor    = csr_src + 500000;        // 1

    hipMemsetAsync(cnt,     0, 50000 * 4, stream);
    hipMemsetAsync(cursor2, 0, 50000 * 4, stream);
    hipMemsetAsync(cursor,  0, 4, stream);
    hipMemsetAsync(a_s2,    0, 50000 * 4, stream);  // gemm2 epilogue atomics
    hipMemsetAsync(a_d2,    0, 50000 * 4, stream);

    // CSR build (shared by both conv layers)
    count_kernel<<<(N_EDGE + 255) / 256, 256, 0, stream>>>(ei, cnt);
    alloc_kernel<<<(N_ENT + 255) / 256, 256, 0, stream>>>(cnt, row_start, cursor);
    fill_csr_kernel<<<(N_EDGE + 255) / 256, 256, 0, stream>>>(ei, row_start, cursor2, csr_src);

    // weight transposes (bf16)
    transpose_bf16_kernel<<<(131072 + 255) / 256, 256, 0, stream>>>(W1, W1T, 256, 512);
    transpose_bf16_kernel<<<(131072 + 255) / 256, 256, 0, stream>>>(W2, W2T, 512, 256);

    // LayerNorm -> bf16
    ln_kernel<<<12500, 256, 0, stream>>>(x, ln_w, ln_b, h0b);

    // --- conv1 (dots fused into gemm epilogue) ---
    gemm_mfma<512, 256, 64><<<dim3(4, 391), 256, 0, stream>>>(
        h0b, W1T, h1b, att_s1, att_d1, a_s1, a_d1, N_ENT);
    aggr1_kernel<<<12500, 256, 0, stream>>>(csr_src, row_start, cnt, h1b, a_s1, a_d1, b1, h2b);

    // --- conv2 ---
    gemm_mfma<256, 512, 256><<<dim3(2, 391), 256, 0, stream>>>(
        h2b, W2T, h3b, att_s2, att_d2, a_s2, a_d2, N_ENT);
    aggr2_kernel<<<12500, 256, 0, stream>>>(csr_src, row_start, cnt, h3b, a_s2, a_d2, b2, out);
}

// Round 7
// 409.871 us; speedup vs baseline: 1.0035x; 1.0035x over previous
//
#include <hip/hip_runtime.h>
#include <hip/hip_bf16.h>
#include <cstdint>

// Problem constants (from reference)
#define N_ENT  50000
#define N_EDGE 500000
#define D_IN   256
constexpr int ETOT = N_EDGE + N_ENT;

typedef __attribute__((ext_vector_type(8))) short bfrag;   // 8 bf16 (4 VGPRs)
typedef __attribute__((ext_vector_type(4))) float f4acc;   // 4 fp32 acc
typedef __attribute__((ext_vector_type(4))) float f32x4;
typedef __attribute__((ext_vector_type(8))) short s16x8;

__device__ __forceinline__ float lrelu(float x) { return x > 0.f ? x : 0.2f * x; }
__device__ __forceinline__ float eluf(float x)  { return x > 0.f ? x : (expf(x) - 1.f); }
__device__ __forceinline__ short to_bf16(float f) {
    __hip_bfloat16 b = __float2bfloat16(f);
    return *(short*)&b;
}
// two packed bf16 -> two floats (lo = bits[15:0], hi = bits[31:16])
__device__ __forceinline__ float2 bf2_to_f32(unsigned int u) {
    float2 r;
    r.x = __uint_as_float(u << 16);
    r.y = __uint_as_float(u & 0xffff0000u);
    return r;
}

// ---------------- LayerNorm: wave per row, bf16 output ----------------
__global__ __launch_bounds__(256) void ln_kernel(const float* __restrict__ x,
        const float* __restrict__ w, const float* __restrict__ b,
        short* __restrict__ y)
{
    int n = blockIdx.x * 4 + (threadIdx.x >> 6);
    int lane = threadIdx.x & 63;
    const f32x4 v = __builtin_nontemporal_load((const f32x4*)(x + (size_t)n * D_IN + lane * 4));
    float s  = v.x + v.y + v.z + v.w;
    float sq = v.x*v.x + v.y*v.y + v.z*v.z + v.w*v.w;
    #pragma unroll
    for (int off = 1; off < 64; off <<= 1) {
        s  += __shfl_xor(s, off);
        sq += __shfl_xor(sq, off);
    }
    float mean = s * (1.f / 256.f);
    float var  = sq * (1.f / 256.f) - mean * mean;
    float rstd = rsqrtf(var + 1e-5f);
    float4 wv = *(const float4*)(w + lane * 4);
    float4 bv = *(const float4*)(b + lane * 4);
    short4 o;
    o.x = to_bf16((v.x - mean) * rstd * wv.x + bv.x);
    o.y = to_bf16((v.y - mean) * rstd * wv.y + bv.y);
    o.z = to_bf16((v.z - mean) * rstd * wv.z + bv.z);
    o.w = to_bf16((v.w - mean) * rstd * wv.w + bv.w);
    *(short4*)(y + (size_t)n * D_IN + lane * 4) = o;
}

// ---------------- transpose + cast: W[R,C] f32 -> WT[C,R] bf16 ----------------
__global__ __launch_bounds__(256) void transpose_bf16_kernel(const float* __restrict__ W,
        short* __restrict__ WT, int R, int C)
{
    int i = blockIdx.x * 256 + threadIdx.x;
    if (i >= R * C) return;
    int r = i / C, c = i - r * C;
    WT[c * R + r] = to_bf16(W[i]);
}

// ---------------- bf16 MFMA GEMM: C[M,NN] = A[M,KK] @ BT[NN,KK]^T, bf16 out ----
template<int NN, int KK>
__global__ __launch_bounds__(256) void gemm_mfma(const short* __restrict__ A,
        const short* __restrict__ BT, short* __restrict__ C, int M)
{
    __shared__ short As[128 * 32];
    __shared__ short Bs[128 * 32];
    const int tid  = threadIdx.x;
    const int w    = tid >> 6;
    const int l    = tid & 63;
    const int wm   = w >> 1, wn = w & 1;
    const int m0   = blockIdx.y * 128;
    const int n0   = blockIdx.x * 128;
    const int quad = l >> 4;
    const int ln16 = l & 15;
    const int rl   = l >> 2;   // staging: row within 16-row issue group
    const int cs   = l & 3;    // staging: chunk slot

    f4acc acc[4][4];
    #pragma unroll
    for (int i = 0; i < 4; ++i)
        #pragma unroll
        for (int j = 0; j < 4; ++j)
            acc[i][j] = (f4acc){0.f, 0.f, 0.f, 0.f};

    for (int k0 = 0; k0 < KK; k0 += 32) {
        __syncthreads();
        #pragma unroll
        for (int tt = 0; tt < 2; ++tt) {
            int t   = w * 2 + tt;          // issue id 0..7 (16 rows each)
            int row = t * 16 + rl;         // local row 0..127
            int ca  = cs ^ ((row >> 1) & 3);
            const short* ga = A + (size_t)(m0 + row) * KK + k0 + ca * 8;
            __builtin_amdgcn_global_load_lds(
                (const __attribute__((address_space(1))) unsigned int*)ga,
                (__attribute__((address_space(3))) unsigned int*)&As[t * 512], 16, 0, 0);
            const short* gb = BT + (size_t)(n0 + row) * KK + k0 + ca * 8;
            __builtin_amdgcn_global_load_lds(
                (const __attribute__((address_space(1))) unsigned int*)gb,
                (__attribute__((address_space(3))) unsigned int*)&Bs[t * 512], 16, 0, 0);
        }
        __syncthreads();
        bfrag af[4], bf[4];
        #pragma unroll
        for (int i = 0; i < 4; ++i) {
            int r = wm * 64 + i * 16 + ln16;           // A row (m)
            af[i] = *(const bfrag*)&As[r * 32 + (quad ^ ((r >> 1) & 3)) * 8];
            int rn = wn * 64 + i * 16 + ln16;          // B col (n)
            bf[i] = *(const bfrag*)&Bs[rn * 32 + (quad ^ ((rn >> 1) & 3)) * 8];
        }
        #pragma unroll
        for (int i = 0; i < 4; ++i)
            #pragma unroll
            for (int j = 0; j < 4; ++j)
                acc[i][j] = __builtin_amdgcn_mfma_f32_16x16x32_bf16(af[i], bf[j], acc[i][j], 0, 0, 0);
    }
    // epilogue: C/D layout col=lane&15, row=quad*4+reg; bf16 store
    #pragma unroll
    for (int i = 0; i < 4; ++i) {
        #pragma unroll
        for (int p = 0; p < 4; ++p) {
            int gr = m0 + wm * 64 + i * 16 + quad * 4 + p;
            if (gr < M) {
                #pragma unroll
                for (int j = 0; j < 4; ++j) {
                    int gc = n0 + wn * 64 + j * 16 + ln16;
                    C[(size_t)gr * NN + gc] = to_bf16(acc[i][j][p]);
                }
            }
        }
    }
}

// ---------------- attention dot products (bf16 feat): wave per node ----------------
template<int H, int C>
__global__ __launch_bounds__(256) void attn_dots_kernel(const short* __restrict__ feat,
        const float* __restrict__ att_s, const float* __restrict__ att_d,
        float* __restrict__ a_s, float* __restrict__ a_d, int N)
{
    constexpr int F = H * C;
    constexpr int PL = F / 64;          // 8 or 4 bf16 per lane
    int n = blockIdx.x * 4 + (threadIdx.x >> 6);
    if (n >= N) return;
    int lane = threadIdx.x & 63;
    int f0 = lane * PL;
    int h = f0 / C;
    float fv[PL];
    const unsigned int* fp = (const unsigned int*)(feat + (size_t)n * F + f0);
    #pragma unroll
    for (int j = 0; j < PL / 2; ++j) {
        float2 t = bf2_to_f32(fp[j]);
        fv[2 * j] = t.x; fv[2 * j + 1] = t.y;
    }
    float ps = 0.f, pd = 0.f;
    #pragma unroll
    for (int j = 0; j < PL; ++j) {
        ps = fmaf(fv[j], att_s[f0 + j], ps);
        pd = fmaf(fv[j], att_d[f0 + j], pd);
    }
    constexpr int GROUP = 64 / H;
    #pragma unroll
    for (int off = 1; off < GROUP; off <<= 1) {
        ps += __shfl_xor(ps, off);
        pd += __shfl_xor(pd, off);
    }
    if ((lane & (GROUP - 1)) == 0) {
        a_s[(size_t)n * H + h] = ps;
        a_d[(size_t)n * H + h] = pd;
    }
}

// ---------------- CSR build ----------------
__global__ __launch_bounds__(256) void count_kernel(const int* __restrict__ ei,
        int* __restrict__ cnt)
{
    int e = blockIdx.x * 256 + threadIdx.x;
    if (e < N_EDGE) atomicAdd(&cnt[ei[N_EDGE + e]], 1);
}

__global__ __launch_bounds__(256) void alloc_kernel(const int* __restrict__ cnt,
        int* __restrict__ row_start, int* __restrict__ cursor)
{
    int d = blockIdx.x * 256 + threadIdx.x;
    int lane = threadIdx.x & 63;
    int c = (d < N_ENT) ? cnt[d] : 0;
    int inc = c;
    #pragma unroll
    for (int off = 1; off < 64; off <<= 1) {
        int nb = __shfl_up(inc, off);
        if (lane >= off) inc += nb;
    }
    int waveTotal = __shfl(inc, 63);
    int base = 0;
    if (lane == 63) base = atomicAdd(cursor, waveTotal);
    base = __shfl(base, 63);
    if (d < N_ENT) row_start[d] = base + inc - c;
}

__global__ __launch_bounds__(256) void fill_csr_kernel(const int* __restrict__ ei,
        const int* __restrict__ row_start, int* __restrict__ cursor2,
        int* __restrict__ csr_src)
{
    int e = blockIdx.x * 256 + threadIdx.x;
    if (e >= N_EDGE) return;
    int d = ei[N_EDGE + e];
    int pos = atomicAdd(&cursor2[d], 1);
    csr_src[row_start[d] + pos] = ei[e];
}

// ---------------- conv1 aggregation: wave per dst, one-pass softmax ----------------
// H=8, C=64, F=512. lane owns 8 contiguous bf16 (16 B); head h = lane>>3.
// No segment-max (shift-invariant, |e|<=~3 so exp can't overflow).
// Unroll x8 for MLP depth; __expf (native v_exp).
__global__ __launch_bounds__(256) void aggr1_kernel(const int* __restrict__ csr_src,
        const int* __restrict__ row_start, const int* __restrict__ cnt,
        const short* __restrict__ feat, const float* __restrict__ a_s,
        const float* __restrict__ a_d, const float* __restrict__ bias,
        short* __restrict__ out)
{
    int d = blockIdx.x * 4 + (threadIdx.x >> 6);
    if (d >= N_ENT) return;
    int lane = threadIdx.x & 63;
    int f0 = lane * 8;
    int h = lane >> 3;
    int rs = row_start[d];
    int n = cnt[d];
    float adh = a_d[d * 8 + h];

    float den = 0.f;
    float acc[8] = {0.f, 0.f, 0.f, 0.f, 0.f, 0.f, 0.f, 0.f};
    // self loop
    {
        float p = __expf(lrelu(a_s[d * 8 + h] + adh));
        den += p;
        uint4 rv = *(const uint4*)(feat + (size_t)d * 512 + f0);
        float2 t0 = bf2_to_f32(rv.x), t1 = bf2_to_f32(rv.y);
        float2 t2 = bf2_to_f32(rv.z), t3 = bf2_to_f32(rv.w);
        acc[0] += p * t0.x; acc[1] += p * t0.y; acc[2] += p * t1.x; acc[3] += p * t1.y;
        acc[4] += p * t2.x; acc[5] += p * t2.y; acc[6] += p * t3.x; acc[7] += p * t3.y;
    }
    int i = 0;
    for (; i + 8 <= n; i += 8) {
        int   sv[8];
        float ev[8];
        uint4 rv[8];
        #pragma unroll
        for (int u = 0; u < 8; ++u) sv[u] = csr_src[rs + i + u];
        #pragma unroll
        for (int u = 0; u < 8; ++u) ev[u] = a_s[sv[u] * 8 + h];
        #pragma unroll
        for (int u = 0; u < 8; ++u) rv[u] = *(const uint4*)(feat + (size_t)sv[u] * 512 + f0);
        #pragma unroll
        for (int u = 0; u < 8; ++u) {
            float p = __expf(lrelu(ev[u] + adh));
            den += p;
            float2 t0 = bf2_to_f32(rv[u].x), t1 = bf2_to_f32(rv[u].y);
            float2 t2 = bf2_to_f32(rv[u].z), t3 = bf2_to_f32(rv[u].w);
            acc[0] += p * t0.x; acc[1] += p * t0.y; acc[2] += p * t1.x; acc[3] += p * t1.y;
            acc[4] += p * t2.x; acc[5] += p * t2.y; acc[6] += p * t3.x; acc[7] += p * t3.y;
        }
    }
    for (; i + 4 <= n; i += 4) {
        int   sv[4];
        float ev[4];
        uint4 rv[4];
        #pragma unroll
        for (int u = 0; u < 4; ++u) sv[u] = csr_src[rs + i + u];
        #pragma unroll
        for (int u = 0; u < 4; ++u) ev[u] = a_s[sv[u] * 8 + h];
        #pragma unroll
        for (int u = 0; u < 4; ++u) rv[u] = *(const uint4*)(feat + (size_t)sv[u] * 512 + f0);
        #pragma unroll
        for (int u = 0; u < 4; ++u) {
            float p = __expf(lrelu(ev[u] + adh));
            den += p;
            float2 t0 = bf2_to_f32(rv[u].x), t1 = bf2_to_f32(rv[u].y);
            float2 t2 = bf2_to_f32(rv[u].z), t3 = bf2_to_f32(rv[u].w);
            acc[0] += p * t0.x; acc[1] += p * t0.y; acc[2] += p * t1.x; acc[3] += p * t1.y;
            acc[4] += p * t2.x; acc[5] += p * t2.y; acc[6] += p * t3.x; acc[7] += p * t3.y;
        }
    }
    for (; i < n; ++i) {
        int s = csr_src[rs + i];
        float p = __expf(lrelu(a_s[s * 8 + h] + adh));
        den += p;
        uint4 rv = *(const uint4*)(feat + (size_t)s * 512 + f0);
        float2 t0 = bf2_to_f32(rv.x), t1 = bf2_to_f32(rv.y);
        float2 t2 = bf2_to_f32(rv.z), t3 = bf2_to_f32(rv.w);
        acc[0] += p * t0.x; acc[1] += p * t0.y; acc[2] += p * t1.x; acc[3] += p * t1.y;
        acc[4] += p * t2.x; acc[5] += p * t2.y; acc[6] += p * t3.x; acc[7] += p * t3.y;
    }
    float inv = 1.f / den;
    float4 b0 = *(const float4*)(bias + f0);
    float4 b1 = *(const float4*)(bias + f0 + 4);
    s16x8 o;
    o[0] = to_bf16(eluf(acc[0] * inv + b0.x)); o[1] = to_bf16(eluf(acc[1] * inv + b0.y));
    o[2] = to_bf16(eluf(acc[2] * inv + b0.z)); o[3] = to_bf16(eluf(acc[3] * inv + b0.w));
    o[4] = to_bf16(eluf(acc[4] * inv + b1.x)); o[5] = to_bf16(eluf(acc[5] * inv + b1.y));
    o[6] = to_bf16(eluf(acc[6] * inv + b1.z)); o[7] = to_bf16(eluf(acc[7] * inv + b1.w));
    __builtin_nontemporal_store(o, (s16x8*)(out + (size_t)d * 512 + f0));
}

// ---------------- conv2 aggregation: wave per dst, half-wave per edge ----------------
// H=1, C=256, F=256 (512 B row = 32 lanes x 16 B). Each 32-lane half processes a
// different edge at full 16 B/lane width; halves combined via xor-32 shuffles.
__global__ __launch_bounds__(256) void aggr2_kernel(const int* __restrict__ csr_src,
        const int* __restrict__ row_start, const int* __restrict__ cnt,
        const short* __restrict__ feat, const float* __restrict__ a_s,
        const float* __restrict__ a_d, const float* __restrict__ bias,
        float* __restrict__ out)
{
    int d = blockIdx.x * 4 + (threadIdx.x >> 6);
    if (d >= N_ENT) return;
    int lane = threadIdx.x & 63;
    int half = lane >> 5;        // 0 or 1: which edge of the pair
    int li   = lane & 31;        // position within row
    int f0   = li * 8;           // 8 bf16 = 16 B per lane
    int rs = row_start[d];
    int n = cnt[d];
    float adh = a_d[d];

    float den = 0.f;
    float acc[8] = {0.f, 0.f, 0.f, 0.f, 0.f, 0.f, 0.f, 0.f};
    // self loop (half 0 only accumulates; both halves load the same line - cache hit)
    {
        float p = (half == 0) ? __expf(lrelu(a_s[d] + adh)) : 0.f;
        uint4 rv = *(const uint4*)(feat + (size_t)d * 256 + f0);
        den += p;
        float2 t0 = bf2_to_f32(rv.x), t1 = bf2_to_f32(rv.y);
        float2 t2 = bf2_to_f32(rv.z), t3 = bf2_to_f32(rv.w);
        acc[0] += p * t0.x; acc[1] += p * t0.y; acc[2] += p * t1.x; acc[3] += p * t1.y;
        acc[4] += p * t2.x; acc[5] += p * t2.y; acc[6] += p * t3.x; acc[7] += p * t3.y;
    }
    int i = 0;
    for (; i + 4 <= n; i += 4) {           // 4 edges per iter (2 per half)
        int e0 = i + half, e1 = i + 2 + half;
        int s0 = csr_src[rs + e0];
        int s1 = csr_src[rs + e1];
        float a0 = a_s[s0], a1 = a_s[s1];
        uint4 rv0 = *(const uint4*)(feat + (size_t)s0 * 256 + f0);
        uint4 rv1 = *(const uint4*)(feat + (size_t)s1 * 256 + f0);
        float p0 = __expf(lrelu(a0 + adh));
        float p1 = __expf(lrelu(a1 + adh));
        den += p0 + p1;
        float2 t0, t1, t2, t3;
        t0 = bf2_to_f32(rv0.x); t1 = bf2_to_f32(rv0.y); t2 = bf2_to_f32(rv0.z); t3 = bf2_to_f32(rv0.w);
        acc[0] += p0 * t0.x; acc[1] += p0 * t0.y; acc[2] += p0 * t1.x; acc[3] += p0 * t1.y;
        acc[4] += p0 * t2.x; acc[5] += p0 * t2.y; acc[6] += p0 * t3.x; acc[7] += p0 * t3.y;
        t0 = bf2_to_f32(rv1.x); t1 = bf2_to_f32(rv1.y); t2 = bf2_to_f32(rv1.z); t3 = bf2_to_f32(rv1.w);
        acc[0] += p1 * t0.x; acc[1] += p1 * t0.y; acc[2] += p1 * t1.x; acc[3] += p1 * t1.y;
        acc[4] += p1 * t2.x; acc[5] += p1 * t2.y; acc[6] += p1 * t3.x; acc[7] += p1 * t3.y;
    }
    for (; i < n; i += 2) {                // pair tail (predicated second half)
        int e = i + half;
        bool valid = e < n;
        int s = valid ? csr_src[rs + e] : d;
        float av = a_s[s];
        uint4 rv = *(const uint4*)(feat + (size_t)s * 256 + f0);
        float p = valid ? __expf(lrelu(av + adh)) : 0.f;
        den += p;
        float2 t0 = bf2_to_f32(rv.x), t1 = bf2_to_f32(rv.y);
        float2 t2 = bf2_to_f32(rv.z), t3 = bf2_to_f32(rv.w);
        acc[0] += p * t0.x; acc[1] += p * t0.y; acc[2] += p * t1.x; acc[3] += p * t1.y;
        acc[4] += p * t2.x; acc[5] += p * t2.y; acc[6] += p * t3.x; acc[7] += p * t3.y;
    }
    // combine halves (lane li pairs with lane li+32, same columns)
    den += __shfl_xor(den, 32);
    #pragma unroll
    for (int k = 0; k < 8; ++k) acc[k] += __shfl_xor(acc[k], 32);

    float inv = 1.f / den;
    if (half == 0) {
        float4 b0 = *(const float4*)(bias + f0);
        float4 b1 = *(const float4*)(bias + f0 + 4);
        f32x4 o0, o1;
        o0.x = acc[0] * inv + b0.x; o0.y = acc[1] * inv + b0.y;
        o0.z = acc[2] * inv + b0.z; o0.w = acc[3] * inv + b0.w;
        o1.x = acc[4] * inv + b1.x; o1.y = acc[5] * inv + b1.y;
        o1.z = acc[6] * inv + b1.z; o1.w = acc[7] * inv + b1.w;
        __builtin_nontemporal_store(o0, (f32x4*)(out + (size_t)d * 256 + f0));
        __builtin_nontemporal_store(o1, (f32x4*)(out + (size_t)d * 256 + f0 + 4));
    }
}

extern "C" void kernel_launch(void* const* d_in, const int* in_sizes, int n_in,
                              void* d_out, int out_size, void* d_ws, size_t ws_size,
                              hipStream_t stream)
{
    const int*   ei     = (const int*)  d_in[0];
    const float* x      = (const float*)d_in[1];
    const float* ln_w   = (const float*)d_in[2];
    const float* ln_b   = (const float*)d_in[3];
    const float* W1     = (const float*)d_in[4];
    const float* att_s1 = (const float*)d_in[5];
    const float* att_d1 = (const float*)d_in[6];
    const float* b1     = (const float*)d_in[7];
    const float* W2     = (const float*)d_in[8];
    const float* att_s2 = (const float*)d_in[9];
    const float* att_d2 = (const float*)d_in[10];
    const float* b2     = (const float*)d_in[11];
    float* out = (float*)d_out;

    short* h0b = (short*)d_ws;                // [50000,256] bf16 LN out
    short* h1b = h0b + 12800000;              // [50000,512] bf16 gemm1 out
    short* h2b = h1b + 25600000;              // [50000,512] bf16 conv1 out
    short* h3b = h2b + 25600000;              // [50000,256] bf16 gemm2 out
    short* W1T = h3b + 12800000;              // [512,256] bf16
    short* W2T = W1T + 131072;                // [256,512] bf16
    float* a_s1 = (float*)(W2T + 131072);     // [50000,8]
    float* a_d1 = a_s1 + 400000;
    float* a_s2 = a_d1 + 400000;              // [50000]
    float* a_d2 = a_s2 + 50000;
    int* cnt       = (int*)(a_d2 + 50000);    // 50000
    int* row_start = cnt + 50000;
    int* cursor2   = row_start + 50000;
    int* csr_src   = cursor2 + 50000;         // 500000
    int* cursor    = csr_src + 500000;        // 1

    hipMemsetAsync(cnt,     0, 50000 * 4, stream);
    hipMemsetAsync(cursor2, 0, 50000 * 4, stream);
    hipMemsetAsync(cursor,  0, 4, stream);

    // CSR build (shared by both conv layers)
    count_kernel<<<(N_EDGE + 255) / 256, 256, 0, stream>>>(ei, cnt);
    alloc_kernel<<<(N_ENT + 255) / 256, 256, 0, stream>>>(cnt, row_start, cursor);
    fill_csr_kernel<<<(N_EDGE + 255) / 256, 256, 0, stream>>>(ei, row_start, cursor2, csr_src);

    // weight transposes (bf16)
    transpose_bf16_kernel<<<(131072 + 255) / 256, 256, 0, stream>>>(W1, W1T, 256, 512);
    transpose_bf16_kernel<<<(131072 + 255) / 256, 256, 0, stream>>>(W2, W2T, 512, 256);

    // LayerNorm -> bf16
    ln_kernel<<<12500, 256, 0, stream>>>(x, ln_w, ln_b, h0b);

    // --- conv1 ---
    gemm_mfma<512, 256><<<dim3(4, 391), 256, 0, stream>>>(h0b, W1T, h1b, N_ENT);
    attn_dots_kernel<8, 64><<<12500, 256, 0, stream>>>(h1b, att_s1, att_d1, a_s1, a_d1, N_ENT);
    aggr1_kernel<<<12500, 256, 0, stream>>>(csr_src, row_start, cnt, h1b, a_s1, a_d1, b1, h2b);

    // --- conv2 ---
    gemm_mfma<256, 512><<<dim3(2, 391), 256, 0, stream>>>(h2b, W2T, h3b, N_ENT);
    attn_dots_kernel<1, 256><<<12500, 256, 0, stream>>>(h3b, att_s2, att_d2, a_s2, a_d2, N_ENT);
    aggr2_kernel<<<12500, 256, 0, stream>>>(csr_src, row_start, cnt, h3b, a_s2, a_d2, b2, out);
}

// Round 8
// 403.909 us; speedup vs baseline: 1.0183x; 1.0148x over previous
//
#include <hip/hip_runtime.h>
#include <hip/hip_bf16.h>
#include <cstdint>

// Problem constants (from reference)
#define N_ENT  50000
#define N_EDGE 500000
#define D_IN   256
constexpr int ETOT = N_EDGE + N_ENT;

typedef __attribute__((ext_vector_type(8))) short bfrag;   // 8 bf16 (4 VGPRs)
typedef __attribute__((ext_vector_type(4))) float f4acc;   // 4 fp32 acc
typedef __attribute__((ext_vector_type(4))) float f32x4;
typedef __attribute__((ext_vector_type(8))) short s16x8;

__device__ __forceinline__ float lrelu(float x) { return x > 0.f ? x : 0.2f * x; }
__device__ __forceinline__ float eluf(float x)  { return x > 0.f ? x : (expf(x) - 1.f); }
__device__ __forceinline__ short to_bf16(float f) {
    __hip_bfloat16 b = __float2bfloat16(f);
    return *(short*)&b;
}
// two packed bf16 -> two floats (lo = bits[15:0], hi = bits[31:16])
__device__ __forceinline__ float2 bf2_to_f32(unsigned int u) {
    float2 r;
    r.x = __uint_as_float(u << 16);
    r.y = __uint_as_float(u & 0xffff0000u);
    return r;
}

// ---------------- fused prep: LN + edge count + both weight transposes ----------------
// Sections by blockIdx (wave-uniform divergence):
//   [0,12500)        LayerNorm, 4 rows/block
//   [12500,14454)    count: histogram of edge destinations
//   [14454,14966)    W1 [256,512] -> W1T [512,256] bf16
//   [14966,15478)    W2 [512,256] -> W2T [256,512] bf16
__global__ __launch_bounds__(256) void prep_kernel(const float* __restrict__ x,
        const float* __restrict__ lnw, const float* __restrict__ lnb,
        short* __restrict__ y, const int* __restrict__ ei, int* __restrict__ cnt,
        const float* __restrict__ W1, short* __restrict__ W1T,
        const float* __restrict__ W2, short* __restrict__ W2T)
{
    int blk = blockIdx.x;
    if (blk < 12500) {
        int n = blk * 4 + (threadIdx.x >> 6);
        int lane = threadIdx.x & 63;
        const f32x4 v = __builtin_nontemporal_load((const f32x4*)(x + (size_t)n * D_IN + lane * 4));
        float s  = v.x + v.y + v.z + v.w;
        float sq = v.x*v.x + v.y*v.y + v.z*v.z + v.w*v.w;
        #pragma unroll
        for (int off = 1; off < 64; off <<= 1) {
            s  += __shfl_xor(s, off);
            sq += __shfl_xor(sq, off);
        }
        float mean = s * (1.f / 256.f);
        float var  = sq * (1.f / 256.f) - mean * mean;
        float rstd = rsqrtf(var + 1e-5f);
        float4 wv = *(const float4*)(lnw + lane * 4);
        float4 bv = *(const float4*)(lnb + lane * 4);
        short4 o;
        o.x = to_bf16((v.x - mean) * rstd * wv.x + bv.x);
        o.y = to_bf16((v.y - mean) * rstd * wv.y + bv.y);
        o.z = to_bf16((v.z - mean) * rstd * wv.z + bv.z);
        o.w = to_bf16((v.w - mean) * rstd * wv.w + bv.w);
        *(short4*)(y + (size_t)n * D_IN + lane * 4) = o;
    } else if (blk < 14454) {
        int e = (blk - 12500) * 256 + threadIdx.x;
        if (e < N_EDGE) atomicAdd(&cnt[ei[N_EDGE + e]], 1);
    } else if (blk < 14966) {
        int i = (blk - 14454) * 256 + threadIdx.x;     // < 131072, W1[256,512]
        int r = i >> 9, c = i & 511;
        W1T[c * 256 + r] = to_bf16(W1[i]);
    } else {
        int i = (blk - 14966) * 256 + threadIdx.x;     // < 131072, W2[512,256]
        int r = i >> 8, c = i & 255;
        W2T[c * 512 + r] = to_bf16(W2[i]);
    }
}

// ---------------- bf16 MFMA GEMM (+optional fused dots, CH=64 only) ----------------
// C[M,NN] = A[M,KK] @ BT[NN,KK]^T, bf16 out. 128x128 tile, BK=32, 4 waves.
template<int NN, int KK, bool FUSE_DOTS>
__global__ __launch_bounds__(256) void gemm_mfma(const short* __restrict__ A,
        const short* __restrict__ BT, short* __restrict__ C,
        const float* __restrict__ att_s, const float* __restrict__ att_d,
        float* __restrict__ a_s, float* __restrict__ a_d, int M)
{
    __shared__ short As[128 * 32];
    __shared__ short Bs[128 * 32];
    const int tid  = threadIdx.x;
    const int w    = tid >> 6;
    const int l    = tid & 63;
    const int wm   = w >> 1, wn = w & 1;
    const int m0   = blockIdx.y * 128;
    const int n0   = blockIdx.x * 128;
    const int quad = l >> 4;
    const int ln16 = l & 15;
    const int rl   = l >> 2;   // staging: row within 16-row issue group
    const int cs   = l & 3;    // staging: chunk slot

    f4acc acc[4][4];
    #pragma unroll
    for (int i = 0; i < 4; ++i)
        #pragma unroll
        for (int j = 0; j < 4; ++j)
            acc[i][j] = (f4acc){0.f, 0.f, 0.f, 0.f};

    for (int k0 = 0; k0 < KK; k0 += 32) {
        __syncthreads();
        #pragma unroll
        for (int tt = 0; tt < 2; ++tt) {
            int t   = w * 2 + tt;          // issue id 0..7 (16 rows each)
            int row = t * 16 + rl;         // local row 0..127
            int ca  = cs ^ ((row >> 1) & 3);
            const short* ga = A + (size_t)(m0 + row) * KK + k0 + ca * 8;
            __builtin_amdgcn_global_load_lds(
                (const __attribute__((address_space(1))) unsigned int*)ga,
                (__attribute__((address_space(3))) unsigned int*)&As[t * 512], 16, 0, 0);
            const short* gb = BT + (size_t)(n0 + row) * KK + k0 + ca * 8;
            __builtin_amdgcn_global_load_lds(
                (const __attribute__((address_space(1))) unsigned int*)gb,
                (__attribute__((address_space(3))) unsigned int*)&Bs[t * 512], 16, 0, 0);
        }
        __syncthreads();
        bfrag af[4], bf[4];
        #pragma unroll
        for (int i = 0; i < 4; ++i) {
            int r = wm * 64 + i * 16 + ln16;           // A row (m)
            af[i] = *(const bfrag*)&As[r * 32 + (quad ^ ((r >> 1) & 3)) * 8];
            int rn = wn * 64 + i * 16 + ln16;          // B col (n)
            bf[i] = *(const bfrag*)&Bs[rn * 32 + (quad ^ ((rn >> 1) & 3)) * 8];
        }
        #pragma unroll
        for (int i = 0; i < 4; ++i)
            #pragma unroll
            for (int j = 0; j < 4; ++j)
                acc[i][j] = __builtin_amdgcn_mfma_f32_16x16x32_bf16(af[i], bf[j], acc[i][j], 0, 0, 0);
    }

    // att coefficients for this lane's 4 owned columns (head width 64 = wave col span)
    float as_c[4], ad_c[4];
    if constexpr (FUSE_DOTS) {
        #pragma unroll
        for (int j = 0; j < 4; ++j) {
            int gc = n0 + wn * 64 + j * 16 + ln16;
            as_c[j] = att_s[gc];
            ad_c[j] = att_d[gc];
        }
    }
    const int hh = (n0 + wn * 64) >> 6;    // head index (CH=64)

    // epilogue: C/D layout col=lane&15, row=quad*4+reg; bf16 store (+dots)
    #pragma unroll
    for (int i = 0; i < 4; ++i) {
        #pragma unroll
        for (int p = 0; p < 4; ++p) {
            int gr = m0 + wm * 64 + i * 16 + quad * 4 + p;
            float ps = 0.f, pd = 0.f;
            if constexpr (FUSE_DOTS) {
                #pragma unroll
                for (int j = 0; j < 4; ++j) {
                    float c = acc[i][j][p];
                    ps = fmaf(c, as_c[j], ps);
                    pd = fmaf(c, ad_c[j], pd);
                }
                #pragma unroll
                for (int off = 1; off < 16; off <<= 1) {
                    ps += __shfl_xor(ps, off);
                    pd += __shfl_xor(pd, off);
                }
            }
            if (gr < M) {
                #pragma unroll
                for (int j = 0; j < 4; ++j) {
                    int gc = n0 + wn * 64 + j * 16 + ln16;
                    C[(size_t)gr * NN + gc] = to_bf16(acc[i][j][p]);
                }
                if constexpr (FUSE_DOTS) {
                    if (ln16 == 0) {
                        a_s[(size_t)gr * (NN / 64) + hh] = ps;
                        a_d[(size_t)gr * (NN / 64) + hh] = pd;
                    }
                }
            }
        }
    }
}

// ---------------- attention dot products (bf16 feat): wave per node ----------------
template<int H, int C>
__global__ __launch_bounds__(256) void attn_dots_kernel(const short* __restrict__ feat,
        const float* __restrict__ att_s, const float* __restrict__ att_d,
        float* __restrict__ a_s, float* __restrict__ a_d, int N)
{
    constexpr int F = H * C;
    constexpr int PL = F / 64;
    int n = blockIdx.x * 4 + (threadIdx.x >> 6);
    if (n >= N) return;
    int lane = threadIdx.x & 63;
    int f0 = lane * PL;
    int h = f0 / C;
    float fv[PL];
    const unsigned int* fp = (const unsigned int*)(feat + (size_t)n * F + f0);
    #pragma unroll
    for (int j = 0; j < PL / 2; ++j) {
        float2 t = bf2_to_f32(fp[j]);
        fv[2 * j] = t.x; fv[2 * j + 1] = t.y;
    }
    float ps = 0.f, pd = 0.f;
    #pragma unroll
    for (int j = 0; j < PL; ++j) {
        ps = fmaf(fv[j], att_s[f0 + j], ps);
        pd = fmaf(fv[j], att_d[f0 + j], pd);
    }
    constexpr int GROUP = 64 / H;
    #pragma unroll
    for (int off = 1; off < GROUP; off <<= 1) {
        ps += __shfl_xor(ps, off);
        pd += __shfl_xor(pd, off);
    }
    if ((lane & (GROUP - 1)) == 0) {
        a_s[(size_t)n * H + h] = ps;
        a_d[(size_t)n * H + h] = pd;
    }
}

// ---------------- CSR build ----------------
__global__ __launch_bounds__(256) void alloc_kernel(const int* __restrict__ cnt,
        int* __restrict__ row_start, int* __restrict__ cursor)
{
    int d = blockIdx.x * 256 + threadIdx.x;
    int lane = threadIdx.x & 63;
    int c = (d < N_ENT) ? cnt[d] : 0;
    int inc = c;
    #pragma unroll
    for (int off = 1; off < 64; off <<= 1) {
        int nb = __shfl_up(inc, off);
        if (lane >= off) inc += nb;
    }
    int waveTotal = __shfl(inc, 63);
    int base = 0;
    if (lane == 63) base = atomicAdd(cursor, waveTotal);
    base = __shfl(base, 63);
    if (d < N_ENT) row_start[d] = base + inc - c;
}

__global__ __launch_bounds__(256) void fill_csr_kernel(const int* __restrict__ ei,
        const int* __restrict__ row_start, int* __restrict__ cursor2,
        int* __restrict__ csr_src)
{
    int e = blockIdx.x * 256 + threadIdx.x;
    if (e >= N_EDGE) return;
    int d = ei[N_EDGE + e];
    int pos = atomicAdd(&cursor2[d], 1);
    csr_src[row_start[d] + pos] = ei[e];
}

// ---------------- conv1 aggregation: wave per dst, one-pass softmax ----------------
// H=8, C=64, F=512. lane owns 8 contiguous bf16 (16 B); head h = lane>>3.
// No segment-max (shift-invariant, |e|<=~3 so exp can't overflow). Unroll x4.
__global__ __launch_bounds__(256) void aggr1_kernel(const int* __restrict__ csr_src,
        const int* __restrict__ row_start, const int* __restrict__ cnt,
        const short* __restrict__ feat, const float* __restrict__ a_s,
        const float* __restrict__ a_d, const float* __restrict__ bias,
        short* __restrict__ out)
{
    int d = blockIdx.x * 4 + (threadIdx.x >> 6);
    if (d >= N_ENT) return;
    int lane = threadIdx.x & 63;
    int f0 = lane * 8;
    int h = lane >> 3;
    int rs = row_start[d];
    int n = cnt[d];
    float adh = a_d[d * 8 + h];

    float den = 0.f;
    float acc[8] = {0.f, 0.f, 0.f, 0.f, 0.f, 0.f, 0.f, 0.f};
    // self loop
    {
        float p = __expf(lrelu(a_s[d * 8 + h] + adh));
        den += p;
        uint4 rv = *(const uint4*)(feat + (size_t)d * 512 + f0);
        float2 t0 = bf2_to_f32(rv.x), t1 = bf2_to_f32(rv.y);
        float2 t2 = bf2_to_f32(rv.z), t3 = bf2_to_f32(rv.w);
        acc[0] += p * t0.x; acc[1] += p * t0.y; acc[2] += p * t1.x; acc[3] += p * t1.y;
        acc[4] += p * t2.x; acc[5] += p * t2.y; acc[6] += p * t3.x; acc[7] += p * t3.y;
    }
    int i = 0;
    for (; i + 4 <= n; i += 4) {
        int   sv[4];
        float ev[4];
        uint4 rv[4];
        #pragma unroll
        for (int u = 0; u < 4; ++u) sv[u] = csr_src[rs + i + u];
        #pragma unroll
        for (int u = 0; u < 4; ++u) ev[u] = a_s[sv[u] * 8 + h];
        #pragma unroll
        for (int u = 0; u < 4; ++u) rv[u] = *(const uint4*)(feat + (size_t)sv[u] * 512 + f0);
        #pragma unroll
        for (int u = 0; u < 4; ++u) {
            float p = __expf(lrelu(ev[u] + adh));
            den += p;
            float2 t0 = bf2_to_f32(rv[u].x), t1 = bf2_to_f32(rv[u].y);
            float2 t2 = bf2_to_f32(rv[u].z), t3 = bf2_to_f32(rv[u].w);
            acc[0] += p * t0.x; acc[1] += p * t0.y; acc[2] += p * t1.x; acc[3] += p * t1.y;
            acc[4] += p * t2.x; acc[5] += p * t2.y; acc[6] += p * t3.x; acc[7] += p * t3.y;
        }
    }
    for (; i < n; ++i) {
        int s = csr_src[rs + i];
        float p = __expf(lrelu(a_s[s * 8 + h] + adh));
        den += p;
        uint4 rv = *(const uint4*)(feat + (size_t)s * 512 + f0);
        float2 t0 = bf2_to_f32(rv.x), t1 = bf2_to_f32(rv.y);
        float2 t2 = bf2_to_f32(rv.z), t3 = bf2_to_f32(rv.w);
        acc[0] += p * t0.x; acc[1] += p * t0.y; acc[2] += p * t1.x; acc[3] += p * t1.y;
        acc[4] += p * t2.x; acc[5] += p * t2.y; acc[6] += p * t3.x; acc[7] += p * t3.y;
    }
    float inv = 1.f / den;
    float4 b0 = *(const float4*)(bias + f0);
    float4 b1 = *(const float4*)(bias + f0 + 4);
    s16x8 o;
    o[0] = to_bf16(eluf(acc[0] * inv + b0.x)); o[1] = to_bf16(eluf(acc[1] * inv + b0.y));
    o[2] = to_bf16(eluf(acc[2] * inv + b0.z)); o[3] = to_bf16(eluf(acc[3] * inv + b0.w));
    o[4] = to_bf16(eluf(acc[4] * inv + b1.x)); o[5] = to_bf16(eluf(acc[5] * inv + b1.y));
    o[6] = to_bf16(eluf(acc[6] * inv + b1.z)); o[7] = to_bf16(eluf(acc[7] * inv + b1.w));
    __builtin_nontemporal_store(o, (s16x8*)(out + (size_t)d * 512 + f0));
}

// ---------------- conv2 aggregation: wave per dst, half-wave per edge ----------------
// H=1, C=256, F=256 (512 B row = 32 lanes x 16 B). Each 32-lane half processes a
// different edge at full 16 B/lane width; halves combined via xor-32 shuffles.
__global__ __launch_bounds__(256) void aggr2_kernel(const int* __restrict__ csr_src,
        const int* __restrict__ row_start, const int* __restrict__ cnt,
        const short* __restrict__ feat, const float* __restrict__ a_s,
        const float* __restrict__ a_d, const float* __restrict__ bias,
        float* __restrict__ out)
{
    int d = blockIdx.x * 4 + (threadIdx.x >> 6);
    if (d >= N_ENT) return;
    int lane = threadIdx.x & 63;
    int half = lane >> 5;
    int li   = lane & 31;
    int f0   = li * 8;
    int rs = row_start[d];
    int n = cnt[d];
    float adh = a_d[d];

    float den = 0.f;
    float acc[8] = {0.f, 0.f, 0.f, 0.f, 0.f, 0.f, 0.f, 0.f};
    {
        float p = (half == 0) ? __expf(lrelu(a_s[d] + adh)) : 0.f;
        uint4 rv = *(const uint4*)(feat + (size_t)d * 256 + f0);
        den += p;
        float2 t0 = bf2_to_f32(rv.x), t1 = bf2_to_f32(rv.y);
        float2 t2 = bf2_to_f32(rv.z), t3 = bf2_to_f32(rv.w);
        acc[0] += p * t0.x; acc[1] += p * t0.y; acc[2] += p * t1.x; acc[3] += p * t1.y;
        acc[4] += p * t2.x; acc[5] += p * t2.y; acc[6] += p * t3.x; acc[7] += p * t3.y;
    }
    int i = 0;
    for (; i + 4 <= n; i += 4) {
        int e0 = i + half, e1 = i + 2 + half;
        int s0 = csr_src[rs + e0];
        int s1 = csr_src[rs + e1];
        float a0 = a_s[s0], a1 = a_s[s1];
        uint4 rv0 = *(const uint4*)(feat + (size_t)s0 * 256 + f0);
        uint4 rv1 = *(const uint4*)(feat + (size_t)s1 * 256 + f0);
        float p0 = __expf(lrelu(a0 + adh));
        float p1 = __expf(lrelu(a1 + adh));
        den += p0 + p1;
        float2 t0, t1, t2, t3;
        t0 = bf2_to_f32(rv0.x); t1 = bf2_to_f32(rv0.y); t2 = bf2_to_f32(rv0.z); t3 = bf2_to_f32(rv0.w);
        acc[0] += p0 * t0.x; acc[1] += p0 * t0.y; acc[2] += p0 * t1.x; acc[3] += p0 * t1.y;
        acc[4] += p0 * t2.x; acc[5] += p0 * t2.y; acc[6] += p0 * t3.x; acc[7] += p0 * t3.y;
        t0 = bf2_to_f32(rv1.x); t1 = bf2_to_f32(rv1.y); t2 = bf2_to_f32(rv1.z); t3 = bf2_to_f32(rv1.w);
        acc[0] += p1 * t0.x; acc[1] += p1 * t0.y; acc[2] += p1 * t1.x; acc[3] += p1 * t1.y;
        acc[4] += p1 * t2.x; acc[5] += p1 * t2.y; acc[6] += p1 * t3.x; acc[7] += p1 * t3.y;
    }
    for (; i < n; i += 2) {
        int e = i + half;
        bool valid = e < n;
        int s = valid ? csr_src[rs + e] : d;
        float av = a_s[s];
        uint4 rv = *(const uint4*)(feat + (size_t)s * 256 + f0);
        float p = valid ? __expf(lrelu(av + adh)) : 0.f;
        den += p;
        float2 t0 = bf2_to_f32(rv.x), t1 = bf2_to_f32(rv.y);
        float2 t2 = bf2_to_f32(rv.z), t3 = bf2_to_f32(rv.w);
        acc[0] += p * t0.x; acc[1] += p * t0.y; acc[2] += p * t1.x; acc[3] += p * t1.y;
        acc[4] += p * t2.x; acc[5] += p * t2.y; acc[6] += p * t3.x; acc[7] += p * t3.y;
    }
    den += __shfl_xor(den, 32);
    #pragma unroll
    for (int k = 0; k < 8; ++k) acc[k] += __shfl_xor(acc[k], 32);

    float inv = 1.f / den;
    if (half == 0) {
        float4 b0 = *(const float4*)(bias + f0);
        float4 b1 = *(const float4*)(bias + f0 + 4);
        f32x4 o0, o1;
        o0.x = acc[0] * inv + b0.x; o0.y = acc[1] * inv + b0.y;
        o0.z = acc[2] * inv + b0.z; o0.w = acc[3] * inv + b0.w;
        o1.x = acc[4] * inv + b1.x; o1.y = acc[5] * inv + b1.y;
        o1.z = acc[6] * inv + b1.z; o1.w = acc[7] * inv + b1.w;
        __builtin_nontemporal_store(o0, (f32x4*)(out + (size_t)d * 256 + f0));
        __builtin_nontemporal_store(o1, (f32x4*)(out + (size_t)d * 256 + f0 + 4));
    }
}

extern "C" void kernel_launch(void* const* d_in, const int* in_sizes, int n_in,
                              void* d_out, int out_size, void* d_ws, size_t ws_size,
                              hipStream_t stream)
{
    const int*   ei     = (const int*)  d_in[0];
    const float* x      = (const float*)d_in[1];
    const float* ln_w   = (const float*)d_in[2];
    const float* ln_b   = (const float*)d_in[3];
    const float* W1     = (const float*)d_in[4];
    const float* att_s1 = (const float*)d_in[5];
    const float* att_d1 = (const float*)d_in[6];
    const float* b1     = (const float*)d_in[7];
    const float* W2     = (const float*)d_in[8];
    const float* att_s2 = (const float*)d_in[9];
    const float* att_d2 = (const float*)d_in[10];
    const float* b2     = (const float*)d_in[11];
    float* out = (float*)d_out;

    short* h0b = (short*)d_ws;                // [50000,256] bf16 LN out
    short* h1b = h0b + 12800000;              // [50000,512] bf16 gemm1 out
    short* h2b = h1b + 25600000;              // [50000,512] bf16 conv1 out
    short* h3b = h2b + 25600000;              // [50000,256] bf16 gemm2 out
    short* W1T = h3b + 12800000;              // [512,256] bf16
    short* W2T = W1T + 131072;                // [256,512] bf16
    float* a_s1 = (float*)(W2T + 131072);     // [50000,8]
    float* a_d1 = a_s1 + 400000;
    float* a_s2 = a_d1 + 400000;              // [50000]
    float* a_d2 = a_s2 + 50000;
    // int workspace: cnt, cursor2, cursor contiguous -> single memset
    int* cnt       = (int*)(a_d2 + 50000);    // 50000
    int* cursor2   = cnt + 50000;             // 50000
    int* cursor    = cursor2 + 50000;         // 1
    int* row_start = cursor + 1;              // 50000
    int* csr_src   = row_start + 50000;       // 500000

    // one memset zeroes cnt + cursor2 + cursor (100001 ints)
    hipMemsetAsync(cnt, 0, 100001 * 4, stream);

    // fused LN + count + weight transposes
    prep_kernel<<<15478, 256, 0, stream>>>(x, ln_w, ln_b, h0b, ei, cnt, W1, W1T, W2, W2T);
    alloc_kernel<<<196, 256, 0, stream>>>(cnt, row_start, cursor);
    fill_csr_kernel<<<1954, 256, 0, stream>>>(ei, row_start, cursor2, csr_src);

    // --- conv1 (dots fused into gemm1 epilogue, plain stores, no atomics) ---
    gemm_mfma<512, 256, true><<<dim3(4, 391), 256, 0, stream>>>(
        h0b, W1T, h1b, att_s1, att_d1, a_s1, a_d1, N_ENT);
    aggr1_kernel<<<12500, 256, 0, stream>>>(csr_src, row_start, cnt, h1b, a_s1, a_d1, b1, h2b);

    // --- conv2 ---
    gemm_mfma<256, 512, false><<<dim3(2, 391), 256, 0, stream>>>(
        h2b, W2T, h3b, nullptr, nullptr, nullptr, nullptr, N_ENT);
    attn_dots_kernel<1, 256><<<12500, 256, 0, stream>>>(h3b, att_s2, att_d2, a_s2, a_d2, N_ENT);
    aggr2_kernel<<<12500, 256, 0, stream>>>(csr_src, row_start, cnt, h3b, a_s2, a_d2, b2, out);
}

// Round 9
// 388.166 us; speedup vs baseline: 1.0596x; 1.0406x over previous
//
#include <hip/hip_runtime.h>
#include <hip/hip_bf16.h>
#include <cstdint>

// Problem constants (from reference)
#define N_ENT  50000
#define N_EDGE 500000
#define D_IN   256
constexpr int ETOT = N_EDGE + N_ENT;

typedef __attribute__((ext_vector_type(8))) short bfrag;   // 8 bf16 (4 VGPRs)
typedef __attribute__((ext_vector_type(4))) float f4acc;   // 4 fp32 acc
typedef __attribute__((ext_vector_type(4))) float f32x4;
typedef __attribute__((ext_vector_type(8))) short s16x8;

__device__ __forceinline__ float lrelu(float x) { return x > 0.f ? x : 0.2f * x; }
__device__ __forceinline__ float eluf(float x)  { return x > 0.f ? x : (expf(x) - 1.f); }
__device__ __forceinline__ short to_bf16(float f) {
    __hip_bfloat16 b = __float2bfloat16(f);
    return *(short*)&b;
}
// two packed bf16 -> two floats (lo = bits[15:0], hi = bits[31:16])
__device__ __forceinline__ float2 bf2_to_f32(unsigned int u) {
    float2 r;
    r.x = __uint_as_float(u << 16);
    r.y = __uint_as_float(u & 0xffff0000u);
    return r;
}

// ---------------- fused prep: LN + edge count + both weight transposes ----------------
//   [0,12500)        LayerNorm, 4 rows/block
//   [12500,14454)    count: histogram of edge destinations
//   [14454,14966)    W1 [256,512] -> W1T [512,256] bf16
//   [14966,15478)    W2 [512,256] -> W2T [256,512] bf16
__global__ __launch_bounds__(256) void prep_kernel(const float* __restrict__ x,
        const float* __restrict__ lnw, const float* __restrict__ lnb,
        short* __restrict__ y, const int* __restrict__ ei, int* __restrict__ cnt,
        const float* __restrict__ W1, short* __restrict__ W1T,
        const float* __restrict__ W2, short* __restrict__ W2T)
{
    int blk = blockIdx.x;
    if (blk < 12500) {
        int n = blk * 4 + (threadIdx.x >> 6);
        int lane = threadIdx.x & 63;
        const f32x4 v = __builtin_nontemporal_load((const f32x4*)(x + (size_t)n * D_IN + lane * 4));
        float s  = v.x + v.y + v.z + v.w;
        float sq = v.x*v.x + v.y*v.y + v.z*v.z + v.w*v.w;
        #pragma unroll
        for (int off = 1; off < 64; off <<= 1) {
            s  += __shfl_xor(s, off);
            sq += __shfl_xor(sq, off);
        }
        float mean = s * (1.f / 256.f);
        float var  = sq * (1.f / 256.f) - mean * mean;
        float rstd = rsqrtf(var + 1e-5f);
        float4 wv = *(const float4*)(lnw + lane * 4);
        float4 bv = *(const float4*)(lnb + lane * 4);
        short4 o;
        o.x = to_bf16((v.x - mean) * rstd * wv.x + bv.x);
        o.y = to_bf16((v.y - mean) * rstd * wv.y + bv.y);
        o.z = to_bf16((v.z - mean) * rstd * wv.z + bv.z);
        o.w = to_bf16((v.w - mean) * rstd * wv.w + bv.w);
        *(short4*)(y + (size_t)n * D_IN + lane * 4) = o;
    } else if (blk < 14454) {
        int e = (blk - 12500) * 256 + threadIdx.x;
        if (e < N_EDGE) atomicAdd(&cnt[ei[N_EDGE + e]], 1);
    } else if (blk < 14966) {
        int i = (blk - 14454) * 256 + threadIdx.x;     // < 131072, W1[256,512]
        int r = i >> 9, c = i & 511;
        W1T[c * 256 + r] = to_bf16(W1[i]);
    } else {
        int i = (blk - 14966) * 256 + threadIdx.x;     // < 131072, W2[512,256]
        int r = i >> 8, c = i & 255;
        W2T[c * 512 + r] = to_bf16(W2[i]);
    }
}

// ---------------- bf16 MFMA GEMM + fused dots + optional CSR-fill tail ----------------
// C[M,NN] = A[M,KK] @ BT[NN,KK]^T, bf16 out. 128x128 tile, BK=32, 4 waves. 1D grid:
// blocks [0,nGemm) do GEMM (bx=blk%GX, by=blk/GX); blocks >= nGemm scatter edges
// into csr_src (DO_FILL only). CH: 0=no dots, 64=per-head plain store, 256=atomic.
template<int NN, int KK, int CH, bool DO_FILL>
__global__ __launch_bounds__(256) void gemm_mfma(const short* __restrict__ A,
        const short* __restrict__ BT, short* __restrict__ C,
        const float* __restrict__ att_s, const float* __restrict__ att_d,
        float* __restrict__ a_s, float* __restrict__ a_d, int M, int nGemm,
        const int* __restrict__ ei, const int* __restrict__ row_start,
        int* __restrict__ cursor2, int* __restrict__ csr_src)
{
    constexpr int GX = NN / 128;
    __shared__ short As[128 * 32];
    __shared__ short Bs[128 * 32];

    if (DO_FILL && (int)blockIdx.x >= nGemm) {
        int e = ((int)blockIdx.x - nGemm) * 256 + threadIdx.x;
        if (e < N_EDGE) {
            int d = ei[N_EDGE + e];
            int pos = atomicAdd(&cursor2[d], 1);
            csr_src[row_start[d] + pos] = ei[e];
        }
        return;
    }

    const int tid  = threadIdx.x;
    const int w    = tid >> 6;
    const int l    = tid & 63;
    const int wm   = w >> 1, wn = w & 1;
    const int m0   = ((int)blockIdx.x / GX) * 128;
    const int n0   = ((int)blockIdx.x % GX) * 128;
    const int quad = l >> 4;
    const int ln16 = l & 15;
    const int rl   = l >> 2;   // staging: row within 16-row issue group
    const int cs   = l & 3;    // staging: chunk slot

    f4acc acc[4][4];
    #pragma unroll
    for (int i = 0; i < 4; ++i)
        #pragma unroll
        for (int j = 0; j < 4; ++j)
            acc[i][j] = (f4acc){0.f, 0.f, 0.f, 0.f};

    for (int k0 = 0; k0 < KK; k0 += 32) {
        __syncthreads();
        #pragma unroll
        for (int tt = 0; tt < 2; ++tt) {
            int t   = w * 2 + tt;          // issue id 0..7 (16 rows each)
            int row = t * 16 + rl;         // local row 0..127
            int ca  = cs ^ ((row >> 1) & 3);
            const short* ga = A + (size_t)(m0 + row) * KK + k0 + ca * 8;
            __builtin_amdgcn_global_load_lds(
                (const __attribute__((address_space(1))) unsigned int*)ga,
                (__attribute__((address_space(3))) unsigned int*)&As[t * 512], 16, 0, 0);
            const short* gb = BT + (size_t)(n0 + row) * KK + k0 + ca * 8;
            __builtin_amdgcn_global_load_lds(
                (const __attribute__((address_space(1))) unsigned int*)gb,
                (__attribute__((address_space(3))) unsigned int*)&Bs[t * 512], 16, 0, 0);
        }
        __syncthreads();
        bfrag af[4], bf[4];
        #pragma unroll
        for (int i = 0; i < 4; ++i) {
            int r = wm * 64 + i * 16 + ln16;           // A row (m)
            af[i] = *(const bfrag*)&As[r * 32 + (quad ^ ((r >> 1) & 3)) * 8];
            int rn = wn * 64 + i * 16 + ln16;          // B col (n)
            bf[i] = *(const bfrag*)&Bs[rn * 32 + (quad ^ ((rn >> 1) & 3)) * 8];
        }
        #pragma unroll
        for (int i = 0; i < 4; ++i)
            #pragma unroll
            for (int j = 0; j < 4; ++j)
                acc[i][j] = __builtin_amdgcn_mfma_f32_16x16x32_bf16(af[i], bf[j], acc[i][j], 0, 0, 0);
    }

    // att coefficients for this lane's 4 owned columns (wave spans 64 cols = one
    // head for CH=64; part of the single head for CH=256)
    float as_c[4], ad_c[4];
    if constexpr (CH > 0) {
        #pragma unroll
        for (int j = 0; j < 4; ++j) {
            int gc = n0 + wn * 64 + j * 16 + ln16;
            as_c[j] = att_s[gc];
            ad_c[j] = att_d[gc];
        }
    }
    const int hh = (n0 + wn * 64) >> 6;    // head index when CH=64

    // epilogue: C/D layout col=lane&15, row=quad*4+reg; bf16 store (+dots)
    #pragma unroll
    for (int i = 0; i < 4; ++i) {
        #pragma unroll
        for (int p = 0; p < 4; ++p) {
            int gr = m0 + wm * 64 + i * 16 + quad * 4 + p;
            float ps = 0.f, pd = 0.f;
            if constexpr (CH > 0) {
                #pragma unroll
                for (int j = 0; j < 4; ++j) {
                    float c = acc[i][j][p];
                    ps = fmaf(c, as_c[j], ps);
                    pd = fmaf(c, ad_c[j], pd);
                }
                #pragma unroll
                for (int off = 1; off < 16; off <<= 1) {
                    ps += __shfl_xor(ps, off);
                    pd += __shfl_xor(pd, off);
                }
            }
            if (gr < M) {
                #pragma unroll
                for (int j = 0; j < 4; ++j) {
                    int gc = n0 + wn * 64 + j * 16 + ln16;
                    C[(size_t)gr * NN + gc] = to_bf16(acc[i][j][p]);
                }
                if constexpr (CH == 64) {
                    if (ln16 == 0) {
                        a_s[(size_t)gr * (NN / 64) + hh] = ps;
                        a_d[(size_t)gr * (NN / 64) + hh] = pd;
                    }
                } else if constexpr (CH == 256) {
                    if (ln16 == 0) {
                        unsafeAtomicAdd(&a_s[gr], ps);
                        unsafeAtomicAdd(&a_d[gr], pd);
                    }
                }
            }
        }
    }
}

// ---------------- CSR alloc: exclusive scan of counts ----------------
__global__ __launch_bounds__(256) void alloc_kernel(const int* __restrict__ cnt,
        int* __restrict__ row_start, int* __restrict__ cursor)
{
    int d = blockIdx.x * 256 + threadIdx.x;
    int lane = threadIdx.x & 63;
    int c = (d < N_ENT) ? cnt[d] : 0;
    int inc = c;
    #pragma unroll
    for (int off = 1; off < 64; off <<= 1) {
        int nb = __shfl_up(inc, off);
        if (lane >= off) inc += nb;
    }
    int waveTotal = __shfl(inc, 63);
    int base = 0;
    if (lane == 63) base = atomicAdd(cursor, waveTotal);
    base = __shfl(base, 63);
    if (d < N_ENT) row_start[d] = base + inc - c;
}

// ---------------- conv1 aggregation: wave per dst, one-pass softmax ----------------
// H=8, C=64, F=512. lane owns 8 contiguous bf16 (16 B); head h = lane>>3.
// No segment-max (shift-invariant, |e|<=~3 so exp can't overflow). Unroll x4.
__global__ __launch_bounds__(256) void aggr1_kernel(const int* __restrict__ csr_src,
        const int* __restrict__ row_start, const int* __restrict__ cnt,
        const short* __restrict__ feat, const float* __restrict__ a_s,
        const float* __restrict__ a_d, const float* __restrict__ bias,
        short* __restrict__ out)
{
    int d = blockIdx.x * 4 + (threadIdx.x >> 6);
    if (d >= N_ENT) return;
    int lane = threadIdx.x & 63;
    int f0 = lane * 8;
    int h = lane >> 3;
    int rs = row_start[d];
    int n = cnt[d];
    float adh = a_d[d * 8 + h];

    float den = 0.f;
    float acc[8] = {0.f, 0.f, 0.f, 0.f, 0.f, 0.f, 0.f, 0.f};
    // self loop
    {
        float p = __expf(lrelu(a_s[d * 8 + h] + adh));
        den += p;
        uint4 rv = *(const uint4*)(feat + (size_t)d * 512 + f0);
        float2 t0 = bf2_to_f32(rv.x), t1 = bf2_to_f32(rv.y);
        float2 t2 = bf2_to_f32(rv.z), t3 = bf2_to_f32(rv.w);
        acc[0] += p * t0.x; acc[1] += p * t0.y; acc[2] += p * t1.x; acc[3] += p * t1.y;
        acc[4] += p * t2.x; acc[5] += p * t2.y; acc[6] += p * t3.x; acc[7] += p * t3.y;
    }
    int i = 0;
    for (; i + 4 <= n; i += 4) {
        int   sv[4];
        float ev[4];
        uint4 rv[4];
        #pragma unroll
        for (int u = 0; u < 4; ++u) sv[u] = csr_src[rs + i + u];
        #pragma unroll
        for (int u = 0; u < 4; ++u) ev[u] = a_s[sv[u] * 8 + h];
        #pragma unroll
        for (int u = 0; u < 4; ++u) rv[u] = *(const uint4*)(feat + (size_t)sv[u] * 512 + f0);
        #pragma unroll
        for (int u = 0; u < 4; ++u) {
            float p = __expf(lrelu(ev[u] + adh));
            den += p;
            float2 t0 = bf2_to_f32(rv[u].x), t1 = bf2_to_f32(rv[u].y);
            float2 t2 = bf2_to_f32(rv[u].z), t3 = bf2_to_f32(rv[u].w);
            acc[0] += p * t0.x; acc[1] += p * t0.y; acc[2] += p * t1.x; acc[3] += p * t1.y;
            acc[4] += p * t2.x; acc[5] += p * t2.y; acc[6] += p * t3.x; acc[7] += p * t3.y;
        }
    }
    for (; i < n; ++i) {
        int s = csr_src[rs + i];
        float p = __expf(lrelu(a_s[s * 8 + h] + adh));
        den += p;
        uint4 rv = *(const uint4*)(feat + (size_t)s * 512 + f0);
        float2 t0 = bf2_to_f32(rv.x), t1 = bf2_to_f32(rv.y);
        float2 t2 = bf2_to_f32(rv.z), t3 = bf2_to_f32(rv.w);
        acc[0] += p * t0.x; acc[1] += p * t0.y; acc[2] += p * t1.x; acc[3] += p * t1.y;
        acc[4] += p * t2.x; acc[5] += p * t2.y; acc[6] += p * t3.x; acc[7] += p * t3.y;
    }
    float inv = 1.f / den;
    float4 b0 = *(const float4*)(bias + f0);
    float4 b1 = *(const float4*)(bias + f0 + 4);
    s16x8 o;
    o[0] = to_bf16(eluf(acc[0] * inv + b0.x)); o[1] = to_bf16(eluf(acc[1] * inv + b0.y));
    o[2] = to_bf16(eluf(acc[2] * inv + b0.z)); o[3] = to_bf16(eluf(acc[3] * inv + b0.w));
    o[4] = to_bf16(eluf(acc[4] * inv + b1.x)); o[5] = to_bf16(eluf(acc[5] * inv + b1.y));
    o[6] = to_bf16(eluf(acc[6] * inv + b1.z)); o[7] = to_bf16(eluf(acc[7] * inv + b1.w));
    __builtin_nontemporal_store(o, (s16x8*)(out + (size_t)d * 512 + f0));
}

// ---------------- conv2 aggregation: wave per dst, half-wave per edge ----------------
// H=1, C=256, F=256 (512 B row = 32 lanes x 16 B). Each 32-lane half processes a
// different edge at full 16 B/lane width; halves combined via xor-32 shuffles.
__global__ __launch_bounds__(256) void aggr2_kernel(const int* __restrict__ csr_src,
        const int* __restrict__ row_start, const int* __restrict__ cnt,
        const short* __restrict__ feat, const float* __restrict__ a_s,
        const float* __restrict__ a_d, const float* __restrict__ bias,
        float* __restrict__ out)
{
    int d = blockIdx.x * 4 + (threadIdx.x >> 6);
    if (d >= N_ENT) return;
    int lane = threadIdx.x & 63;
    int half = lane >> 5;
    int li   = lane & 31;
    int f0   = li * 8;
    int rs = row_start[d];
    int n = cnt[d];
    float adh = a_d[d];

    float den = 0.f;
    float acc[8] = {0.f, 0.f, 0.f, 0.f, 0.f, 0.f, 0.f, 0.f};
    {
        float p = (half == 0) ? __expf(lrelu(a_s[d] + adh)) : 0.f;
        uint4 rv = *(const uint4*)(feat + (size_t)d * 256 + f0);
        den += p;
        float2 t0 = bf2_to_f32(rv.x), t1 = bf2_to_f32(rv.y);
        float2 t2 = bf2_to_f32(rv.z), t3 = bf2_to_f32(rv.w);
        acc[0] += p * t0.x; acc[1] += p * t0.y; acc[2] += p * t1.x; acc[3] += p * t1.y;
        acc[4] += p * t2.x; acc[5] += p * t2.y; acc[6] += p * t3.x; acc[7] += p * t3.y;
    }
    int i = 0;
    for (; i + 4 <= n; i += 4) {
        int e0 = i + half, e1 = i + 2 + half;
        int s0 = csr_src[rs + e0];
        int s1 = csr_src[rs + e1];
        float a0 = a_s[s0], a1 = a_s[s1];
        uint4 rv0 = *(const uint4*)(feat + (size_t)s0 * 256 + f0);
        uint4 rv1 = *(const uint4*)(feat + (size_t)s1 * 256 + f0);
        float p0 = __expf(lrelu(a0 + adh));
        float p1 = __expf(lrelu(a1 + adh));
        den += p0 + p1;
        float2 t0, t1, t2, t3;
        t0 = bf2_to_f32(rv0.x); t1 = bf2_to_f32(rv0.y); t2 = bf2_to_f32(rv0.z); t3 = bf2_to_f32(rv0.w);
        acc[0] += p0 * t0.x; acc[1] += p0 * t0.y; acc[2] += p0 * t1.x; acc[3] += p0 * t1.y;
        acc[4] += p0 * t2.x; acc[5] += p0 * t2.y; acc[6] += p0 * t3.x; acc[7] += p0 * t3.y;
        t0 = bf2_to_f32(rv1.x); t1 = bf2_to_f32(rv1.y); t2 = bf2_to_f32(rv1.z); t3 = bf2_to_f32(rv1.w);
        acc[0] += p1 * t0.x; acc[1] += p1 * t0.y; acc[2] += p1 * t1.x; acc[3] += p1 * t1.y;
        acc[4] += p1 * t2.x; acc[5] += p1 * t2.y; acc[6] += p1 * t3.x; acc[7] += p1 * t3.y;
    }
    for (; i < n; i += 2) {
        int e = i + half;
        bool valid = e < n;
        int s = valid ? csr_src[rs + e] : d;
        float av = a_s[s];
        uint4 rv = *(const uint4*)(feat + (size_t)s * 256 + f0);
        float p = valid ? __expf(lrelu(av + adh)) : 0.f;
        den += p;
        float2 t0 = bf2_to_f32(rv.x), t1 = bf2_to_f32(rv.y);
        float2 t2 = bf2_to_f32(rv.z), t3 = bf2_to_f32(rv.w);
        acc[0] += p * t0.x; acc[1] += p * t0.y; acc[2] += p * t1.x; acc[3] += p * t1.y;
        acc[4] += p * t2.x; acc[5] += p * t2.y; acc[6] += p * t3.x; acc[7] += p * t3.y;
    }
    den += __shfl_xor(den, 32);
    #pragma unroll
    for (int k = 0; k < 8; ++k) acc[k] += __shfl_xor(acc[k], 32);

    float inv = 1.f / den;
    if (half == 0) {
        float4 b0 = *(const float4*)(bias + f0);
        float4 b1 = *(const float4*)(bias + f0 + 4);
        f32x4 o0, o1;
        o0.x = acc[0] * inv + b0.x; o0.y = acc[1] * inv + b0.y;
        o0.z = acc[2] * inv + b0.z; o0.w = acc[3] * inv + b0.w;
        o1.x = acc[4] * inv + b1.x; o1.y = acc[5] * inv + b1.y;
        o1.z = acc[6] * inv + b1.z; o1.w = acc[7] * inv + b1.w;
        __builtin_nontemporal_store(o0, (f32x4*)(out + (size_t)d * 256 + f0));
        __builtin_nontemporal_store(o1, (f32x4*)(out + (size_t)d * 256 + f0 + 4));
    }
}

extern "C" void kernel_launch(void* const* d_in, const int* in_sizes, int n_in,
                              void* d_out, int out_size, void* d_ws, size_t ws_size,
                              hipStream_t stream)
{
    const int*   ei     = (const int*)  d_in[0];
    const float* x      = (const float*)d_in[1];
    const float* ln_w   = (const float*)d_in[2];
    const float* ln_b   = (const float*)d_in[3];
    const float* W1     = (const float*)d_in[4];
    const float* att_s1 = (const float*)d_in[5];
    const float* att_d1 = (const float*)d_in[6];
    const float* b1     = (const float*)d_in[7];
    const float* W2     = (const float*)d_in[8];
    const float* att_s2 = (const float*)d_in[9];
    const float* att_d2 = (const float*)d_in[10];
    const float* b2     = (const float*)d_in[11];
    float* out = (float*)d_out;

    short* h0b = (short*)d_ws;                // [50000,256] bf16 LN out
    short* h1b = h0b + 12800000;              // [50000,512] bf16 gemm1 out
    short* h2b = h1b + 25600000;              // [50000,512] bf16 conv1 out
    short* h3b = h2b + 25600000;              // [50000,256] bf16 gemm2 out
    short* W1T = h3b + 12800000;              // [512,256] bf16
    short* W2T = W1T + 131072;                // [256,512] bf16
    float* a_s1 = (float*)(W2T + 131072);     // [50000,8]
    float* a_d1 = a_s1 + 400000;
    // zero-init region (single memset): a_s2, a_d2, cnt, cursor2, cursor
    float* a_s2 = a_d1 + 400000;              // [50000]
    float* a_d2 = a_s2 + 50000;               // [50000]
    int* cnt       = (int*)(a_d2 + 50000);    // 50000
    int* cursor2   = cnt + 50000;             // 50000
    int* cursor    = cursor2 + 50000;         // 1
    int* row_start = cursor + 1;              // 50000
    int* csr_src   = row_start + 50000;       // 500000

    // one memset zeroes a_s2 + a_d2 + cnt + cursor2 + cursor (200001 words)
    hipMemsetAsync(a_s2, 0, 200001 * 4, stream);

    // fused LN + count + weight transposes
    prep_kernel<<<15478, 256, 0, stream>>>(x, ln_w, ln_b, h0b, ei, cnt, W1, W1T, W2, W2T);
    alloc_kernel<<<196, 256, 0, stream>>>(cnt, row_start, cursor);

    // --- conv1: gemm1 (+fused dots1, plain stores) + CSR-fill tail blocks ---
    constexpr int NG1 = 391 * 4;   // 1564 gemm blocks
    gemm_mfma<512, 256, 64, true><<<NG1 + 1954, 256, 0, stream>>>(
        h0b, W1T, h1b, att_s1, att_d1, a_s1, a_d1, N_ENT, NG1,
        ei, row_start, cursor2, csr_src);
    aggr1_kernel<<<12500, 256, 0, stream>>>(csr_src, row_start, cnt, h1b, a_s1, a_d1, b1, h2b);

    // --- conv2: gemm2 (+fused dots2 via atomics) ---
    constexpr int NG2 = 391 * 2;   // 782 gemm blocks
    gemm_mfma<256, 512, 256, false><<<NG2, 256, 0, stream>>>(
        h2b, W2T, h3b, att_s2, att_d2, a_s2, a_d2, N_ENT, NG2,
        nullptr, nullptr, nullptr, nullptr);
    aggr2_kernel<<<12500, 256, 0, stream>>>(csr_src, row_start, cnt, h3b, a_s2, a_d2, b2, out);
}